// Round 3
// baseline (14146.477 us; speedup 1.0000x reference)
//
#include <hip/hip_runtime.h>
#include <math.h>

#define LAYERS 12
#define EE 1024
#define GG 2730
#define VV 16416
#define EPS 1e-6f
#define NBLK 1024

// ---- workspace layout (float offsets) ----
#define OFF_EK 0
#define OFF_EV 1572864
#define OFF_DS 3145728
#define NSLOT 37
#define OFF_ACC (OFF_DS + NSLOT*2048)
#define ACC_STRIDE 28672
#define AQ 0
#define AK 2048
#define AV 4096
#define AY 6144
#define AQC 8192
#define AY2 10240
#define AA 12288
#define AB2 17748
#define ACC_TOTAL (LAYERS*ACC_STRIDE)
#define OFF_BAR (OFF_ACC + ACC_TOTAL)
#define ZERO_FLOATS (NSLOT*2048 + ACC_TOTAL + 1024)

#define KVL 524288   // floats per layer per cache (2 batches x 256 x 1024)
#define KVB 262144   // floats per batch

struct MegaP {
  const float* enc; const float* keys_in; const float* values_in;
  const int* maski; const int* pt; const int* ti;
  const float* tok; const float* pos; const float* ln_s; const float* ln_b;
  const float* final_b; const float* lm_w;
  const float* pre_sa_b; const float* saq; const float* sak; const float* sav;
  const float* sao; const float* sas; const float* sab;
  const float* pre_ca_b; const float* caq; const float* cao;
  const float* cas; const float* cab;
  const float* g0b; const float* f0; const float* f1; const float* g1b; const float* f2;
  float* logits; float* keys_out; float* values_out; float* ws;
};

__device__ __forceinline__ void red4(float* sm, float& a, float& b, float& c, float& d){
  #pragma unroll
  for(int o=32;o;o>>=1){ a+=__shfl_down(a,o); b+=__shfl_down(b,o); c+=__shfl_down(c,o); d+=__shfl_down(d,o); }
  int w=threadIdx.x>>6, l=threadIdx.x&63;
  __syncthreads();
  if(l==0){ sm[w]=a; sm[4+w]=b; sm[8+w]=c; sm[12+w]=d; }
  __syncthreads();
  a=sm[0]+sm[1]+sm[2]+sm[3]; b=sm[4]+sm[5]+sm[6]+sm[7];
  c=sm[8]+sm[9]+sm[10]+sm[11]; d=sm[12]+sm[13]+sm[14]+sm[15];
}

__device__ __forceinline__ void ln_stats_g(const float* v, int K, float* sm,
    float& mu0, float& rs0, float& mu1, float& rs1){
  float s0=0,q0=0,s1=0,q1=0;
  for(int i=threadIdx.x;i<K;i+=256){ float a=v[i], b=v[K+i]; s0+=a;q0+=a*a;s1+=b;q1+=b*b; }
  red4(sm,s0,q0,s1,q1);
  mu0=s0/K; mu1=s1/K;
  rs0=rsqrtf(fmaxf(q0/K-mu0*mu0,0.f)+EPS);
  rs1=rsqrtf(fmaxf(q1/K-mu1*mu1,0.f)+EPS);
}

__device__ __forceinline__ void ln_stats_l(float (*Ds)[1024], float* sm,
    float& mu0, float& rs0, float& mu1, float& rs1){
  float s0=0,q0=0,s1=0,q1=0;
  for(int i=threadIdx.x;i<EE;i+=256){ float a=Ds[0][i], b=Ds[1][i]; s0+=a;q0+=a*a;s1+=b;q1+=b*b; }
  red4(sm,s0,q0,s1,q1);
  mu0=s0/EE; mu1=s1/EE;
  rs0=rsqrtf(fmaxf(q0/EE-mu0*mu0,0.f)+EPS);
  rs1=rsqrtf(fmaxf(q1/EE-mu1*mu1,0.f)+EPS);
}

// ds3 = dsi + LN(AY)*sas+sab + LN(AY2)*cas+cab  -> Ds
__device__ __forceinline__ void build_ds3(const float* dsi, const float* accL,
    const float* sasl, const float* sabl, const float* casl, const float* cabl,
    float (*Ds)[1024], float* sm){
  float mu0,rs0,mu1,rs1;
  ln_stats_g(accL+AY, EE, sm, mu0,rs0,mu1,rs1);
  for(int i=threadIdx.x;i<EE;i+=256){ float sc=sasl[i], bi=sabl[i];
    Ds[0][i]=dsi[i]    + (accL[AY+i]-mu0)*rs0*sc + bi;
    Ds[1][i]=dsi[EE+i] + (accL[AY+EE+i]-mu1)*rs1*sc + bi; }
  ln_stats_g(accL+AY2, EE, sm, mu0,rs0,mu1,rs1);
  for(int i=threadIdx.x;i<EE;i+=256){ float sc=casl[i], bi=cabl[i];
    Ds[0][i] += (accL[AY2+i]-mu0)*rs0*sc + bi;
    Ds[1][i] += (accL[AY2+EE+i]-mu1)*rs1*sc + bi; }
}

// 2-level grid barrier: 32 group counters -> master -> gen. Timeout valve.
__device__ __forceinline__ void gridbar(int* bar, int myg){
  __syncthreads();
  if (threadIdx.x==0){
    __threadfence();
    int grp = blockIdx.x & 31;
    int v = atomicAdd(&bar[grp*16], 1);
    if (v == (NBLK/32)-1){
      __hip_atomic_store(&bar[grp*16], 0, __ATOMIC_RELAXED, __HIP_MEMORY_SCOPE_AGENT);
      int m = atomicAdd(&bar[512], 1);
      if (m == 31){
        __hip_atomic_store(&bar[512], 0, __ATOMIC_RELAXED, __HIP_MEMORY_SCOPE_AGENT);
        __hip_atomic_fetch_add(&bar[520], 1, __ATOMIC_RELEASE, __HIP_MEMORY_SCOPE_AGENT);
      }
    }
    int it=0;
    while (__hip_atomic_load(&bar[520], __ATOMIC_ACQUIRE, __HIP_MEMORY_SCOPE_AGENT) <= myg){
      __builtin_amdgcn_s_sleep(4);
      if (++it > (1<<20)) break;   // safety valve: fail absmax, don't hang
    }
    __threadfence();
  }
  __syncthreads();
}

// batched ek/ev precompute: out[l][row][:] = enc[row][:] @ W[l]
// grid (32, 24): 128-row x 32-col tiles
__global__ __launch_bounds__(256)
void k_ekev(const float* __restrict__ enc, const float* __restrict__ ckw,
            const float* __restrict__ cvw, float* __restrict__ ws){
  int lp = blockIdx.y; int l = lp>>1, proj = lp&1;
  const float* Wt = (proj? cvw : ckw) + (size_t)l*EE*EE;
  float* out = ws + (proj? OFF_EV : OFF_EK) + (size_t)l*128*EE;
  int c0 = blockIdx.x*32;
  __shared__ float As[128][33];
  __shared__ float Bs[32][33];
  int t=threadIdx.x, tx=t&7, ty=t>>3;
  float acc[4][4];
  #pragma unroll
  for(int i=0;i<4;i++){ acc[i][0]=0;acc[i][1]=0;acc[i][2]=0;acc[i][3]=0; }
  for (int k0=0;k0<EE;k0+=32){
    for (int i=t;i<128*32;i+=256){ int r=i>>5, k=i&31; As[r][k] = enc[(size_t)r*EE + k0+k]; }
    for (int i=t;i<32*32;i+=256){ int k=i>>5, c=i&31; Bs[k][c] = Wt[(size_t)(k0+k)*EE + c0+c]; }
    __syncthreads();
    #pragma unroll 8
    for (int k=0;k<32;k++){
      float b0=Bs[k][tx*4+0], b1=Bs[k][tx*4+1], b2=Bs[k][tx*4+2], b3=Bs[k][tx*4+3];
      #pragma unroll
      for (int rr=0;rr<4;rr++){
        float av = As[ty+32*rr][k];
        acc[rr][0]+=av*b0; acc[rr][1]+=av*b1; acc[rr][2]+=av*b2; acc[rr][3]+=av*b3;
      }
    }
    __syncthreads();
  }
  #pragma unroll
  for (int rr=0;rr<4;rr++)
    #pragma unroll
    for (int j=0;j<4;j++)
      out[(size_t)(ty+32*rr)*EE + c0 + tx*4+j] = acc[rr][j];
}

__global__ __launch_bounds__(256, 4)
void k_mega(MegaP p){
  __shared__ float Xs[2][2736];
  __shared__ float Ds[2][1024];
  __shared__ float att[2][256];
  __shared__ float sm[16];

  const int t = threadIdx.x;
  const int bkid = blockIdx.x;
  int* bar = (int*)(p.ws + OFF_BAR);
  const int tiv = p.ti[0];
  int g = 0;

  // ---- prelude (block 0): ds0 = LN(tok[pt]+pos[ti], s, b), atomic into zeroed slot0
  if (bkid==0){
    int ptv = p.pt[0];
    float s0=0,q0=0,d1=0,d2=0;
    for(int i=t;i<EE;i+=256){ float v=p.tok[(size_t)ptv*EE+i]+p.pos[(size_t)tiv*EE+i]; Xs[0][i]=v; s0+=v; q0+=v*v; }
    red4(sm,s0,q0,d1,d2);
    float mu=s0/EE, rs=rsqrtf(fmaxf(q0/EE-mu*mu,0.f)+EPS);
    float* ds0 = p.ws + OFF_DS;
    for(int i=t;i<EE;i+=256){ float y=(Xs[0][i]-mu)*rs*p.ln_s[i]+p.ln_b[i]; atomicAdd(&ds0[i],y); atomicAdd(&ds0[EE+i],y); }
  }
  gridbar(bar, g++);

  for (int l=0;l<LAYERS;l++){
    float* accL = p.ws + OFF_ACC + (size_t)l*ACC_STRIDE;
    const float* dsi = p.ws + OFF_DS + (size_t)(3*l)*2048;
    float* ds4 = p.ws + OFF_DS + (size_t)(3*l+3)*2048;
    const size_t lE2 = (size_t)l*EE*EE;
    const size_t lE  = (size_t)l*EE;
    const size_t lEG = (size_t)l*EE*GG;
    const size_t lGE = (size_t)l*GG*EE;
    const size_t lG  = (size_t)l*GG;

    // ===== stage A: x=LN(dsi)+pre_sa_b ; q,k,v GEMV (768 blocks) + KV copy (256 blocks)
    if (bkid < 768){
      float mu0,rs0,mu1,rs1;
      ln_stats_g(dsi, EE, sm, mu0,rs0,mu1,rs1);
      for(int i=t;i<EE;i+=256){ float bi=p.pre_sa_b[lE+i];
        Xs[0][i]=(dsi[i]-mu0)*rs0+bi; Xs[1][i]=(dsi[EE+i]-mu1)*rs1+bi; }
      __syncthreads();
      int cg = bkid % 12, ks = bkid / 12;     // 12 cg x 64 ks, CH=16
      int c = cg*256 + t;
      int sel = c >> 10, cc = c & 1023;
      const float* W = (sel==0? p.saq : sel==1? p.sak : p.sav) + lE2;
      float* O = accL + (sel==0? AQ : sel==1? AK : AV);
      int k0 = ks*16;
      float a0=0,a1=0;
      const float* wp = W + (size_t)k0*EE + cc;
      #pragma unroll 4
      for(int k=0;k<16;k++){ float w=*wp; wp+=EE; a0+=Xs[0][k0+k]*w; a1+=Xs[1][k0+k]*w; }
      atomicAdd(&O[cc],a0); atomicAdd(&O[EE+cc],a1);
    } else {
      int bi = bkid - 768;                     // 256 copy blocks: this layer's KV slice
      #pragma unroll
      for(int j=0;j<4;j++){
        int idx4 = bi*1024 + j*256 + t;        // 262144 float4 per layer
        int e4 = idx4 & 255, tt=(idx4>>8)&255, bb2=(idx4>>16)&1, kv=(idx4>>17)&1;
        if (tt==tiv) continue;                 // row ti written by stage C
        size_t off = (size_t)l*KVL + (size_t)bb2*KVB + (size_t)tt*EE + (size_t)e4*4;
        float4 v = *(const float4*)((kv? p.values_in : p.keys_in) + off);
        *(float4*)((kv? p.values_out : p.keys_out) + off) = v;
      }
    }
    gridbar(bar, g++);

    // ===== stage C: self-attention (inline) + y = attn @ sao  (256 blocks)
    if (bkid < 256){
      int cg=bkid&3, h=(bkid>>2)&15, sub=(bkid>>6)&3, hoff=h*64;
      if (t < 128){ int bb2=t>>6, c2=t&63; Ds[bb2][c2] = accL[AQ + bb2*EE + hoff + c2]*0.125f; }
      __syncthreads();
      for(int bb2=0;bb2<2;bb2++)
        for(int tt=t; tt<=tiv; tt+=256){
          const float* kr = (tt<tiv) ? (p.keys_in + (size_t)l*KVL + (size_t)bb2*KVB + (size_t)tt*EE + hoff)
                                     : (accL + AK + bb2*EE + hoff);
          float d=0;
          #pragma unroll
          for(int c2=0;c2<64;c2++) d += Ds[bb2][c2]*kr[c2];
          att[bb2][tt] = d;
        }
      __syncthreads();
      int wv=t>>6, l2=t&63;
      if (wv<2){
        float m=-3.4e38f;
        for(int tt=l2; tt<=tiv; tt+=64) m=fmaxf(m, att[wv][tt]);
        #pragma unroll
        for(int o=32;o;o>>=1) m=fmaxf(m,__shfl_xor(m,o));
        float s=0;
        for(int tt=l2; tt<=tiv; tt+=64){ float e=__expf(att[wv][tt]-m); att[wv][tt]=e; s+=e; }
        #pragma unroll
        for(int o=32;o;o>>=1) s+=__shfl_xor(s,o);
        if(l2==0) sm[8+wv]=1.f/s;
      }
      __syncthreads();
      {
        int bb2=t>>7, j=(t>>3)&15, part=t&7, colh=sub*16+j;
        float v=0;
        for(int tt=part; tt<=tiv; tt+=8){
          float vv = (tt<tiv)? p.values_in[(size_t)l*KVL + (size_t)bb2*KVB + (size_t)tt*EE + hoff + colh]
                             : accL[AV + bb2*EE + hoff + colh];
          v += att[bb2][tt]*vv;
        }
        v += __shfl_down(v,4,8); v += __shfl_down(v,2,8); v += __shfl_down(v,1,8);
        if(part==0) Ds[bb2][512+j] = v*sm[8+bb2];
      }
      __syncthreads();
      {
        int c = cg*256+t, kb = hoff + sub*16;
        const float* wp = p.sao + lE2 + (size_t)kb*EE + c;
        float a0=0,a1=0;
        #pragma unroll
        for(int j2=0;j2<16;j2++){ float w=wp[(size_t)j2*EE]; a0+=Ds[0][512+j2]*w; a1+=Ds[1][512+j2]*w; }
        atomicAdd(&accL[AY+c],a0); atomicAdd(&accL[AY+EE+c],a1);
      }
      if (cg==0 && sub==0){    // write new KV row for head h
        int bb2=t>>7, kv=(t>>6)&1, c2=t&63;
        float val = accL[(kv?AV:AK) + bb2*EE + hoff + c2];
        float* dst = (kv? p.values_out : p.keys_out)
                   + (size_t)l*KVL + (size_t)bb2*KVB + (size_t)tiv*EE + hoff + c2;
        *dst = val;
      }
    }
    gridbar(bar, g++);

    // ===== stage D: ds2 = dsi + LN(y)*sas+sab ; x2=LN(ds2)+pre_ca_b ; qc = x2@caq (512 blocks)
    if (bkid < 512){
      float mu0,rs0,mu1,rs1;
      ln_stats_g(accL+AY, EE, sm, mu0,rs0,mu1,rs1);
      for(int i=t;i<EE;i+=256){ float sc=p.sas[lE+i], bi=p.sab[lE+i];
        Ds[0][i]=dsi[i]    + (accL[AY+i]-mu0)*rs0*sc + bi;
        Ds[1][i]=dsi[EE+i] + (accL[AY+EE+i]-mu1)*rs1*sc + bi; }
      ln_stats_l(Ds, sm, mu0,rs0,mu1,rs1);
      for(int i=t;i<EE;i+=256){ float bi=p.pre_ca_b[lE+i];
        Xs[0][i]=(Ds[0][i]-mu0)*rs0+bi; Xs[1][i]=(Ds[1][i]-mu1)*rs1+bi; }
      __syncthreads();
      int cg=bkid&3, ks=bkid>>2;               // 4 cg x 128 ks, CH=8
      int c=cg*256+t, k0=ks*8;
      const float* wp = p.caq + lE2 + (size_t)k0*EE + c;
      float a0=0,a1=0;
      #pragma unroll
      for(int k=0;k<8;k++){ float w=*wp; wp+=EE; a0+=Xs[0][k0+k]*w; a1+=Xs[1][k0+k]*w; }
      atomicAdd(&accL[AQC+c],a0); atomicAdd(&accL[AQC+EE+c],a1);
    }
    gridbar(bar, g++);

    // ===== stage F: cross-attention (inline) + y2 = attn2 @ cao (256 blocks)
    if (bkid < 256){
      int cg=bkid&3, h=(bkid>>2)&15, sub=(bkid>>6)&3, hoff=h*64;
      const float* ek = p.ws + OFF_EK;
      const float* ev = p.ws + OFF_EV;
      if (t < 128){ int bb2=t>>6, c2=t&63; Ds[bb2][c2] = accL[AQC + bb2*EE + hoff + c2]*0.125f; }
      __syncthreads();
      if (t < 128){
        int bb2=t>>6, tt=t&63;
        const float* kr = ek + ((size_t)l*128 + bb2*64 + tt)*EE + hoff;
        float d=0;
        #pragma unroll
        for(int c2=0;c2<64;c2++) d += Ds[bb2][c2]*kr[c2];
        int mi = bb2*64+tt;
        bool valid = (p.maski[mi]!=0) || (((const unsigned char*)p.maski)[mi]!=0);
        att[bb2][tt] = valid ? d : -3.4e38f;
      }
      __syncthreads();
      int wv=t>>6, l2=t&63;
      if (wv<2){
        float sc = att[wv][l2];
        float m = sc;
        #pragma unroll
        for(int o=32;o;o>>=1) m=fmaxf(m,__shfl_xor(m,o));
        float e = (sc>-1e37f)? __expf(sc-m) : 0.f;
        att[wv][l2]=e; float s=e;
        #pragma unroll
        for(int o=32;o;o>>=1) s+=__shfl_xor(s,o);
        if(l2==0) sm[8+wv]=1.f/s;
      }
      __syncthreads();
      {
        int bb2=t>>7, j=(t>>3)&15, part=t&7, colh=sub*16+j;
        float v=0;
        for(int tt=part; tt<64; tt+=8)
          v += att[bb2][tt]*ev[((size_t)l*128 + bb2*64 + tt)*EE + hoff + colh];
        v += __shfl_down(v,4,8); v += __shfl_down(v,2,8); v += __shfl_down(v,1,8);
        if(part==0) Ds[bb2][512+j] = v*sm[8+bb2];
      }
      __syncthreads();
      {
        int c = cg*256+t, kb = hoff + sub*16;
        const float* wp = p.cao + lE2 + (size_t)kb*EE + c;
        float a0=0,a1=0;
        #pragma unroll
        for(int j2=0;j2<16;j2++){ float w=wp[(size_t)j2*EE]; a0+=Ds[0][512+j2]*w; a1+=Ds[1][512+j2]*w; }
        atomicAdd(&accL[AY2+c],a0); atomicAdd(&accL[AY2+EE+c],a1);
      }
    }
    gridbar(bar, g++);

    // ===== stage G: ds3 chain ; z=LN(ds3)+g0b ; a=z@f0, b=z@f1 (1012 blocks)
    if (bkid < 1012){
      build_ds3(dsi, accL, p.sas+lE, p.sab+lE, p.cas+lE, p.cab+lE, Ds, sm);
      float mu0,rs0,mu1,rs1;
      ln_stats_l(Ds, sm, mu0,rs0,mu1,rs1);
      for(int i=t;i<EE;i+=256){ float bi=p.g0b[lE+i];
        Xs[0][i]=(Ds[0][i]-mu0)*rs0+bi; Xs[1][i]=(Ds[1][i]-mu1)*rs1+bi; }
      __syncthreads();
      int cg = bkid % 22, ks = bkid / 22;      // 22 cg x 46 ks, CH=23
      int k0 = ks*23;
      if (k0 < EE){
        int k1 = k0+23; if (k1>EE) k1=EE;
        int c = cg*256+t;
        if (c < 5460){
          int sel = (c>=GG), cc = sel? c-GG : c;
          const float* W = (sel? p.f1 : p.f0) + lEG;
          float* O = accL + (sel? AB2 : AA);
          const float* wp = W + (size_t)k0*GG + cc;
          float a0=0,a1=0;
          #pragma unroll 4
          for(int k=k0;k<k1;k++){ float w=*wp; wp+=GG; a0+=Xs[0][k]*w; a1+=Xs[1][k]*w; }
          atomicAdd(&O[cc],a0); atomicAdd(&O[GG+cc],a1);
        }
      }
    }
    gridbar(bar, g++);

    // ===== stage H: t=gelu(a)*b ; z2=LN(t)+g1b ; ds4 = ds3 + z2@f2 (680 blocks)
    if (bkid < 680){
      int cg=bkid&3, ks=bkid>>2;               // 4 cg x 170 ks, CH=17
      if (ks==0) build_ds3(dsi, accL, p.sas+lE, p.sab+lE, p.cas+lE, p.cab+lE, Ds, sm);
      float s0=0,q0=0,s1=0,q1=0;
      for(int i=t;i<GG;i+=256){
        float a0v=accL[AA+i], a1v=accL[AA+GG+i];
        float b0v=accL[AB2+i], b1v=accL[AB2+GG+i];
        float g0v=0.5f*a0v*(1.f+erff(a0v*0.70710678118654752f));
        float g1v=0.5f*a1v*(1.f+erff(a1v*0.70710678118654752f));
        float t0=g0v*b0v, t1=g1v*b1v;
        Xs[0][i]=t0; Xs[1][i]=t1;
        s0+=t0;q0+=t0*t0;s1+=t1;q1+=t1*t1;
      }
      red4(sm,s0,q0,s1,q1);
      float mu0=s0/GG, mu1=s1/GG;
      float rs0=rsqrtf(fmaxf(q0/GG-mu0*mu0,0.f)+EPS), rs1=rsqrtf(fmaxf(q1/GG-mu1*mu1,0.f)+EPS);
      for(int i=t;i<GG;i+=256){ float bi=p.g1b[lG+i];
        Xs[0][i]=(Xs[0][i]-mu0)*rs0+bi; Xs[1][i]=(Xs[1][i]-mu1)*rs1+bi; }
      __syncthreads();
      int k0=ks*17;
      if (k0 < GG){
        int k1=k0+17; if (k1>GG) k1=GG;
        int c=cg*256+t;
        float a0 = (ks==0)? Ds[0][c] : 0.f;
        float a1 = (ks==0)? Ds[1][c] : 0.f;
        const float* wp = p.f2 + lGE + (size_t)k0*EE + c;
        #pragma unroll 4
        for(int k=k0;k<k1;k++){ float w=*wp; wp+=EE; a0+=Xs[0][k]*w; a1+=Xs[1][k]*w; }
        atomicAdd(&ds4[c],a0); atomicAdd(&ds4[EE+c],a1);
      }
    }
    gridbar(bar, g++);
  }

  // ===== final: logits = (LN(ds,final_b)) @ lm_head (975 blocks)
  if (bkid < 975){
    const float* dsf = p.ws + OFF_DS + (size_t)36*2048;
    float mu0,rs0,mu1,rs1;
    ln_stats_g(dsf, EE, sm, mu0,rs0,mu1,rs1);
    for(int i=t;i<EE;i+=256){ float bi=p.final_b[i];
      Xs[0][i]=(dsf[i]-mu0)*rs0+bi; Xs[1][i]=(dsf[EE+i]-mu1)*rs1+bi; }
    __syncthreads();
    int cg=bkid%65, ks=bkid/65;                // 65 cg x 15 ks, CH=69
    int k0=ks*69, k1=k0+69; if (k1>EE) k1=EE;
    int c=cg*256+t;
    if (c < VV && k0 < EE){
      const float* wp = p.lm_w + (size_t)k0*VV + c;
      float a0=0,a1=0;
      #pragma unroll 4
      for(int k=k0;k<k1;k++){ float w=*wp; wp+=VV; a0+=Xs[0][k]*w; a1+=Xs[1][k]*w; }
      atomicAdd(&p.logits[c],a0); atomicAdd(&p.logits[VV+c],a1);
    }
  }
}

extern "C" void kernel_launch(void* const* d_in, const int* in_sizes, int n_in,
                              void* d_out, int out_size, void* d_ws, size_t ws_size,
                              hipStream_t stream){
  (void)in_sizes; (void)n_in; (void)out_size; (void)ws_size;
  float* out = (float*)d_out;
  float* ws = (float*)d_ws;

  MegaP P;
  P.enc        = (const float*)d_in[0];
  P.keys_in    = (const float*)d_in[1];
  P.values_in  = (const float*)d_in[2];
  P.maski      = (const int*)d_in[3];
  P.pt         = (const int*)d_in[4];
  P.ti         = (const int*)d_in[5];
  P.tok        = (const float*)d_in[6];
  P.pos        = (const float*)d_in[7];
  P.ln_s       = (const float*)d_in[8];
  P.ln_b       = (const float*)d_in[9];
  P.final_b    = (const float*)d_in[10];
  P.lm_w       = (const float*)d_in[11];
  P.pre_sa_b   = (const float*)d_in[12];
  P.saq        = (const float*)d_in[13];
  P.sak        = (const float*)d_in[14];
  P.sav        = (const float*)d_in[15];
  P.sao        = (const float*)d_in[16];
  P.sas        = (const float*)d_in[17];
  P.sab        = (const float*)d_in[18];
  P.pre_ca_b   = (const float*)d_in[19];
  P.caq        = (const float*)d_in[20];
  const float* cak = (const float*)d_in[21];
  const float* cav = (const float*)d_in[22];
  P.cao        = (const float*)d_in[23];
  P.cas        = (const float*)d_in[24];
  P.cab        = (const float*)d_in[25];
  P.g0b        = (const float*)d_in[26];
  P.f0         = (const float*)d_in[27];
  P.f1         = (const float*)d_in[28];
  P.g1b        = (const float*)d_in[29];
  P.f2         = (const float*)d_in[30];
  P.logits     = out;
  P.keys_out   = out + (size_t)2*VV;
  P.values_out = P.keys_out + (size_t)LAYERS*KVL;
  P.ws         = ws;

  hipMemsetAsync(ws + OFF_DS, 0, (size_t)ZERO_FLOATS*sizeof(float), stream);
  hipMemsetAsync(P.logits, 0, (size_t)2*VV*sizeof(float), stream);

  k_ekev<<<dim3(32,24),256,0,stream>>>(P.enc, cak, cav, ws);
  k_mega<<<NBLK,256,0,stream>>>(P);
}